// Round 8
// baseline (289.620 us; speedup 1.0000x reference)
//
#include <hip/hip_runtime.h>
#include <stdint.h>

// ChessMultiStageAttention: B=4096 fused blocks of (pos-add, LN, QKV, 8-head
// attention S=64 D=8 with chess bias, out-proj, residual). f32 I/O, bf16 MFMA
// (16x16x32_bf16) with f32 accum.
//
// Round-12 (resubmit; previous bench died to container infra, no data): ONE
// batch item per 256-thread WG (round-11 structure with the `it` dimension
// stripped). Rationale: counters show ~95% latency stall at 3 WG/CU (12
// waves). 1-item WG halves LDS (53248 -> 26624) -> 6 WG/CU (24 waves), grid
// 2048 -> 4096 (finer pipelining, smaller tail), and halves per-wave register
// state so __launch_bounds__(256,6) (85-VGPR cap) fits without spills.
// Weight/bias/pos loads lose their 2-item amortization but are small and
// L2-hot.
//
// Kept from rounds 8-11: bias folded into score-MFMA accumulator (C-layout ==
// bias tile layout, pre-scaled by log2e); softmax scale folded into Q at the
// stage-D store; wave-local heads {2w,2w+1} (no barrier between QKV and
// attention); KA register cache per hl; P bounced through the wave's own
// consumed v^T rows; AO overwrites own heads' K cols.
//
// MFMA layouts (m89-verified):
//   A: lane m=lane&15 holds row m, k=(lane>>4)*8+j (k-contiguous 16B)
//   B: lane holds col n=lane&15, k=(lane>>4)*8+j
//   C/D: col=lane&15, row=(lane>>4)*4+reg
//
// LDS (26624 B -> 6 WG/CU):
//   P1 [64][136] bf16: (A-B) f32 x+pos view [64][68] / (D) Q cols 0..63
//       (pre-scaled), K cols 64..127 / (E) AO overwrites own heads' K cols
//   P2 [64][72]  bf16: (C) x_norm -> XF regs / (D-E) v^T [(h,d)][t] /
//       (E) wave w's v rows 16w..16w+15 double as the P-scratch buffer

typedef __attribute__((ext_vector_type(8))) __bf16 bfrag;
typedef __attribute__((ext_vector_type(4))) __bf16 bf4;
typedef __attribute__((ext_vector_type(4))) float f32x4;

#define MFMA16(a, b, c) __builtin_amdgcn_mfma_f32_16x16x32_bf16((a), (b), (c), 0, 0, 0)

static __device__ __forceinline__ bfrag bsplat(float v) {
  bfrag z;
#pragma unroll
  for (int i = 0; i < 8; i++) z[i] = (__bf16)v;
  return z;
}

static __device__ __forceinline__ bfrag cvt8(const float* __restrict__ p) {
  float4 a = *(const float4*)p, b = *(const float4*)(p + 4);
  bfrag r;
  r[0] = (__bf16)a.x; r[1] = (__bf16)a.y; r[2] = (__bf16)a.z; r[3] = (__bf16)a.w;
  r[4] = (__bf16)b.x; r[5] = (__bf16)b.y; r[6] = (__bf16)b.z; r[7] = (__bf16)b.w;
  return r;
}

__global__ __launch_bounds__(256, 6) void chess_attn_kernel(
    const float* __restrict__ xg,    const float* __restrict__ posg,
    const float* __restrict__ gam,   const float* __restrict__ bet,
    const float* __restrict__ qkvw,  const float* __restrict__ qkvb,
    const float* __restrict__ outw,  const float* __restrict__ outb,
    const float* __restrict__ biasg, float* __restrict__ outg) {
  __shared__ __attribute__((aligned(16))) __bf16 P1[64 * 136];  // 17408 B
  __shared__ __attribute__((aligned(16))) __bf16 P2[64 * 72];   //  9216 B

  const int tid = threadIdx.x, lane = tid & 63, w = tid >> 6;
  const int m = lane & 15, g = lane >> 4;
  const int b = blockIdx.x;
  const float LN2I = 1.4426950408889634f;                        // log2(e)
  const float SCL2 = 0.35355339059327373f * 1.4426950408889634f; // (1/sqrt8)*log2e

  // ---- A: x + pos -> P1 as f32 [64][68]; wave w fills rows 16w..16w+15 ----
  {
    float* XP = (float*)P1;
    const float4* pp = (const float4*)(posg + (size_t)lane * 64 + w * 16);
    const float4* px = (const float4*)(xg + ((size_t)b * 64 + lane) * 64 + w * 16);
#pragma unroll
    for (int v = 0; v < 4; v++) {
      float4 xv = px[v], pv = pp[v];
      const int s = w * 16 + v * 4;
      XP[(s + 0) * 68 + lane] = xv.x + pv.x;
      XP[(s + 1) * 68 + lane] = xv.y + pv.y;
      XP[(s + 2) * 68 + lane] = xv.z + pv.z;
      XP[(s + 3) * 68 + lane] = xv.w + pv.w;
    }
  }
  // no barrier: stage B thread reads row tid>>2, written by its own wave

  // ---- B+C: LayerNorm (4 threads/row, quad shuffle) -> XN in P2 ----
  {
    const int s = tid >> 2, q = tid & 3;
    const float* XP = (const float*)P1;
    const float4* pg = (const float4*)(gam + q * 16);
    const float4* pb = (const float4*)(bet + q * 16);
    float4 g0 = pg[0], g1 = pg[1], g2 = pg[2], g3 = pg[3];
    float4 b0v = pb[0], b1 = pb[1], b2 = pb[2], b3 = pb[3];
    float gr[16] = {g0.x, g0.y, g0.z, g0.w, g1.x, g1.y, g1.z, g1.w,
                    g2.x, g2.y, g2.z, g2.w, g3.x, g3.y, g3.z, g3.w};
    float br[16] = {b0v.x, b0v.y, b0v.z, b0v.w, b1.x, b1.y, b1.z, b1.w,
                    b2.x, b2.y, b2.z, b2.w, b3.x, b3.y, b3.z, b3.w};
    const float4* pr = (const float4*)&XP[s * 68 + q * 16];
    float4 x0 = pr[0], x1 = pr[1], x2 = pr[2], x3 = pr[3];
    float xr[16] = {x0.x, x0.y, x0.z, x0.w, x1.x, x1.y, x1.z, x1.w,
                    x2.x, x2.y, x2.z, x2.w, x3.x, x3.y, x3.z, x3.w};
    float sum = 0.f, ss = 0.f;
#pragma unroll
    for (int i = 0; i < 16; i++) { sum += xr[i]; ss = fmaf(xr[i], xr[i], ss); }
    sum += __shfl_xor(sum, 1); ss += __shfl_xor(ss, 1);
    sum += __shfl_xor(sum, 2); ss += __shfl_xor(ss, 2);
    const float mu = sum * 0.015625f;
    const float rs = __builtin_amdgcn_rsqf(ss * 0.015625f - mu * mu + 1e-5f);
    bfrag o0, o1;
#pragma unroll
    for (int i = 0; i < 8; i++) o0[i] = (__bf16)((xr[i] - mu) * rs * gr[i] + br[i]);
#pragma unroll
    for (int i = 0; i < 8; i++) o1[i] = (__bf16)((xr[8 + i] - mu) * rs * gr[8 + i] + br[8 + i]);
    *(bfrag*)&P2[s * 72 + q * 16] = o0;
    *(bfrag*)&P2[s * 72 + q * 16 + 8] = o1;
  }
  __syncthreads();   // #1: XN visible to all waves

  // ---- D: QKV. XF frags then Q/K/V ----
  bfrag XF[4][2];
#pragma unroll
  for (int st = 0; st < 4; st++) {
    XF[st][0] = *(const bfrag*)&P2[(st * 16 + m) * 72 + g * 8];
    XF[st][1] = *(const bfrag*)&P2[(st * 16 + m) * 72 + 32 + g * 8];
  }
  __syncthreads();   // #2: XF loaded everywhere; V may now overwrite P2

  {
    // Q and K tiles, transposed (A=W rows n, B=XN): wave w -> n-tiles w, w+4
    // Q (i==0) pre-scaled by SCL2 so stage E is exp2(sc) directly.
#pragma unroll
    for (int i = 0; i < 2; i++) {
      const int nt = w + 4 * i;                       // 0..7 (Q: 0-3, K: 4-7)
      bfrag AW0 = cvt8(qkvw + (size_t)(nt * 16 + m) * 64 + g * 8);
      bfrag AW1 = cvt8(qkvw + (size_t)(nt * 16 + m) * 64 + 32 + g * 8);
      float4 qb4 = *(const float4*)(qkvb + nt * 16 + g * 4);
      const float qs = (i == 0) ? SCL2 : 1.0f;
      const float qbx = qb4.x * qs, qby = qb4.y * qs;
      const float qbz = qb4.z * qs, qbw = qb4.w * qs;
#pragma unroll
      for (int st = 0; st < 4; st++) {
        f32x4 c = {0.f, 0.f, 0.f, 0.f};
        c = MFMA16(AW0, XF[st][0], c);                // C: col=s, rows=n
        c = MFMA16(AW1, XF[st][1], c);
        bf4 pk;
        pk[0] = (__bf16)fmaf(c[0], qs, qbx); pk[1] = (__bf16)fmaf(c[1], qs, qby);
        pk[2] = (__bf16)fmaf(c[2], qs, qbz); pk[3] = (__bf16)fmaf(c[3], qs, qbw);
        *(bf4*)&P1[(st * 16 + m) * 136 + nt * 16 + g * 4] = pk;
      }
    }
    // V (A=XN rows s, B=W cols n): wave w -> v^T rows 16w..16w+15
    {
      const int n = 128 + w * 16 + m;
      bfrag BV0 = cvt8(qkvw + (size_t)n * 64 + g * 8);
      bfrag BV1 = cvt8(qkvw + (size_t)n * 64 + 32 + g * 8);
      const float vb = qkvb[n];
#pragma unroll
      for (int st = 0; st < 4; st++) {
        f32x4 c = {0.f, 0.f, 0.f, 0.f};
        c = MFMA16(XF[st][0], BV0, c);                // C: col=v-row, rows=s
        c = MFMA16(XF[st][1], BV1, c);
        bf4 pk;
#pragma unroll
        for (int r = 0; r < 4; r++) pk[r] = (__bf16)(c[r] + vb);
        *(bf4*)&P2[(w * 16 + m) * 72 + st * 16 + g * 4] = pk;
      }
    }
  }
  // NO barrier: stage E of wave w consumes only wave-w-produced Q/K/V
  // (Q cols 16w.., K cols 64+16w.., v rows 16w..); same-wave DS ordering.

  // ---- E: attention, heads h = 2w, 2w+1 (wave-local). S^T = K*Q^T with
  //      bias*log2e accumulator init; P bounced through the wave's own
  //      consumed-v rows; AO overwrites own heads' K cols (KA in regs). ----
  const bfrag ZF  = bsplat(0.f);
  const bfrag ONE = bsplat(1.f);
  const int rowoff = (16 * w + m) * 72;     // wave-private scratch row (s'=m)

  bfrag VA[2][2];   // [hl][kf] — fully hoisted before scratch overlays v rows
#pragma unroll
  for (int hl = 0; hl < 2; hl++)
#pragma unroll
    for (int kf = 0; kf < 2; kf++)
      VA[hl][kf] = (m < 8)
          ? *(const bfrag*)&P2[(16 * w + 8 * hl + m) * 72 + kf * 32 + g * 8]
          : ((m == 8) ? ONE : ZF);

#pragma unroll
  for (int hl = 0; hl < 2; hl++) {
    const int h8 = 16 * w + 8 * hl;       // this wave's head col base (Q; K +64)
    bfrag KA[4];
#pragma unroll
    for (int tt = 0; tt < 4; tt++)
      KA[tt] = (lane < 16) ? *(const bfrag*)&P1[(tt * 16 + m) * 136 + 64 + h8] : ZF;
#pragma unroll
    for (int st = 0; st < 4; st++) {
      // bias tile in C-fragment layout, pre-scaled by log2(e)
      f32x4 binit[4];
#pragma unroll
      for (int tt = 0; tt < 4; tt++) {
        float4 bv = *(const float4*)(biasg + (size_t)(st * 16 + m) * 64 + tt * 16 + g * 4);
        binit[tt][0] = bv.x * LN2I; binit[tt][1] = bv.y * LN2I;
        binit[tt][2] = bv.z * LN2I; binit[tt][3] = bv.w * LN2I;
      }
      bfrag QB = (lane < 16) ? *(const bfrag*)&P1[(st * 16 + m) * 136 + h8] : ZF;
      f32x4 sc[4];
#pragma unroll
      for (int tt = 0; tt < 4; tt++)
        sc[tt] = MFMA16(KA[tt], QB, binit[tt]);   // col=s, rows=t
#pragma unroll
      for (int tt = 0; tt < 4; tt++) {
        bf4 pr;
        pr[0] = (__bf16)__builtin_amdgcn_exp2f(sc[tt][0]);
        pr[1] = (__bf16)__builtin_amdgcn_exp2f(sc[tt][1]);
        pr[2] = (__bf16)__builtin_amdgcn_exp2f(sc[tt][2]);
        pr[3] = (__bf16)__builtin_amdgcn_exp2f(sc[tt][3]);
        *(bf4*)&P2[rowoff + tt * 16 + g * 4] = pr;
      }
      bfrag PB0 = *(const bfrag*)&P2[rowoff + g * 8];
      bfrag PB1 = *(const bfrag*)&P2[rowoff + 32 + g * 8];
      f32x4 oo = {0.f, 0.f, 0.f, 0.f};
      oo = MFMA16(VA[hl][0], PB0, oo);      // O^T: col=s, rows=d; row 8 = sum
      oo = MFMA16(VA[hl][1], PB1, oo);
      const float rsum = __builtin_amdgcn_rcpf(__shfl(oo[0], 32 + m));
      bf4 ov;
#pragma unroll
      for (int r = 0; r < 4; r++) ov[r] = (__bf16)(oo[r] * rsum);
      // AO[s][h*8+d] overwrites this head's K columns (KA is in registers)
      if (g < 2) *(bf4*)&P1[(st * 16 + m) * 136 + 64 + h8 + g * 4] = ov;
    }
  }
  __syncthreads();   // #3: AO complete (cross-wave consumption in F)

  // ---- F: O[s][e] = AO * out_w^T + residual; AO in cols 64..127 ----
  {
    bfrag A0 = *(const bfrag*)&P1[(w * 16 + m) * 136 + 64 + g * 8];
    bfrag A1 = *(const bfrag*)&P1[(w * 16 + m) * 136 + 96 + g * 8];
    const int sbase = w * 16 + g * 4;
    const size_t xoff = (size_t)b * 4096;
#pragma unroll
    for (int et = 0; et < 4; et++) {
      const int e = et * 16 + m;
      bfrag BW0 = cvt8(outw + (size_t)e * 64 + g * 8);
      bfrag BW1 = cvt8(outw + (size_t)e * 64 + 32 + g * 8);
      const float ob = outb[e];
      float4 pv = *(const float4*)(posg + (size_t)e * 64 + sbase);
      f32x4 c = {0.f, 0.f, 0.f, 0.f};
      c = MFMA16(A0, BW0, c);               // col=e, rows=s (4 consec/lane)
      c = MFMA16(A1, BW1, c);
      float4 xv = *(const float4*)(xg + xoff + (size_t)e * 64 + sbase);
      float4 o;
      o.x = c[0] + ob + xv.x + pv.x;
      o.y = c[1] + ob + xv.y + pv.y;
      o.z = c[2] + ob + xv.z + pv.z;
      o.w = c[3] + ob + xv.w + pv.w;
      *(float4*)(outg + xoff + (size_t)e * 64 + sbase) = o;
    }
  }
}

extern "C" void kernel_launch(void* const* d_in, const int* in_sizes, int n_in,
                              void* d_out, int out_size, void* d_ws, size_t ws_size,
                              hipStream_t stream) {
  const float* xg   = (const float*)d_in[0];
  const float* pos  = (const float*)d_in[1];
  const float* gam  = (const float*)d_in[2];
  const float* bet  = (const float*)d_in[3];
  const float* qkvw = (const float*)d_in[4];
  const float* qkvb = (const float*)d_in[5];
  const float* outw = (const float*)d_in[6];
  const float* outb = (const float*)d_in[7];
  const float* cb   = (const float*)d_in[8];
  float* out = (float*)d_out;
  const int B = in_sizes[0] / (64 * 64);   // 4096
  hipLaunchKernelGGL(chess_attn_kernel, dim3(B), dim3(256), 0, stream,
                     xg, pos, gam, bet, qkvw, qkvb, outw, outb, cb, out);
}

// Round 9
// 230.322 us; speedup vs baseline: 1.2575x; 1.2575x over previous
//
#include <hip/hip_runtime.h>
#include <stdint.h>

// ChessMultiStageAttention: B=4096 fused blocks of (pos-add, LN, QKV, 8-head
// attention S=64 D=8 with chess bias, out-proj, residual). f32 I/O, bf16 MFMA
// (16x16x32_bf16) with f32 accum.
//
// Round-13: round-12 kernel with __launch_bounds__(256,4) instead of (256,6).
// Round-12 counters: the (256,6) bound pinned VGPR=40 -> ~480 MB/dispatch
// spill traffic (WRITE 287 MB, FETCH 184 MB) which fully accounts for its
// 195 us. But OccupancyPercent hit 60% (vs 27 at 2-item/WG) — the 1-item
// structure delivers the occupancy. (256,4) caps VGPR at 128; natural demand
// ~64-84 means the HARDWARE still fits 6 waves/SIMD (occupancy from usage,
// not the declared bound — round-7 lesson), with zero spill risk.
//
// Kept from rounds 8-12: bias folded into score-MFMA accumulator (C-layout ==
// bias tile layout, pre-scaled by log2e); softmax scale folded into Q at the
// stage-D store; wave-local heads {2w,2w+1} (no barrier between QKV and
// attention); KA register cache per hl; P bounced through the wave's own
// consumed v^T rows; AO overwrites own heads' K cols.
//
// MFMA layouts (m89-verified):
//   A: lane m=lane&15 holds row m, k=(lane>>4)*8+j (k-contiguous 16B)
//   B: lane holds col n=lane&15, k=(lane>>4)*8+j
//   C/D: col=lane&15, row=(lane>>4)*4+reg
//
// LDS (26624 B -> 6 WG/CU):
//   P1 [64][136] bf16: (A-B) f32 x+pos view [64][68] / (D) Q cols 0..63
//       (pre-scaled), K cols 64..127 / (E) AO overwrites own heads' K cols
//   P2 [64][72]  bf16: (C) x_norm -> XF regs / (D-E) v^T [(h,d)][t] /
//       (E) wave w's v rows 16w..16w+15 double as the P-scratch buffer

typedef __attribute__((ext_vector_type(8))) __bf16 bfrag;
typedef __attribute__((ext_vector_type(4))) __bf16 bf4;
typedef __attribute__((ext_vector_type(4))) float f32x4;

#define MFMA16(a, b, c) __builtin_amdgcn_mfma_f32_16x16x32_bf16((a), (b), (c), 0, 0, 0)

static __device__ __forceinline__ bfrag bsplat(float v) {
  bfrag z;
#pragma unroll
  for (int i = 0; i < 8; i++) z[i] = (__bf16)v;
  return z;
}

static __device__ __forceinline__ bfrag cvt8(const float* __restrict__ p) {
  float4 a = *(const float4*)p, b = *(const float4*)(p + 4);
  bfrag r;
  r[0] = (__bf16)a.x; r[1] = (__bf16)a.y; r[2] = (__bf16)a.z; r[3] = (__bf16)a.w;
  r[4] = (__bf16)b.x; r[5] = (__bf16)b.y; r[6] = (__bf16)b.z; r[7] = (__bf16)b.w;
  return r;
}

__global__ __launch_bounds__(256, 4) void chess_attn_kernel(
    const float* __restrict__ xg,    const float* __restrict__ posg,
    const float* __restrict__ gam,   const float* __restrict__ bet,
    const float* __restrict__ qkvw,  const float* __restrict__ qkvb,
    const float* __restrict__ outw,  const float* __restrict__ outb,
    const float* __restrict__ biasg, float* __restrict__ outg) {
  __shared__ __attribute__((aligned(16))) __bf16 P1[64 * 136];  // 17408 B
  __shared__ __attribute__((aligned(16))) __bf16 P2[64 * 72];   //  9216 B

  const int tid = threadIdx.x, lane = tid & 63, w = tid >> 6;
  const int m = lane & 15, g = lane >> 4;
  const int b = blockIdx.x;
  const float LN2I = 1.4426950408889634f;                        // log2(e)
  const float SCL2 = 0.35355339059327373f * 1.4426950408889634f; // (1/sqrt8)*log2e

  // ---- A: x + pos -> P1 as f32 [64][68]; wave w fills rows 16w..16w+15 ----
  {
    float* XP = (float*)P1;
    const float4* pp = (const float4*)(posg + (size_t)lane * 64 + w * 16);
    const float4* px = (const float4*)(xg + ((size_t)b * 64 + lane) * 64 + w * 16);
#pragma unroll
    for (int v = 0; v < 4; v++) {
      float4 xv = px[v], pv = pp[v];
      const int s = w * 16 + v * 4;
      XP[(s + 0) * 68 + lane] = xv.x + pv.x;
      XP[(s + 1) * 68 + lane] = xv.y + pv.y;
      XP[(s + 2) * 68 + lane] = xv.z + pv.z;
      XP[(s + 3) * 68 + lane] = xv.w + pv.w;
    }
  }
  // no barrier: stage B thread reads row tid>>2, written by its own wave

  // ---- B+C: LayerNorm (4 threads/row, quad shuffle) -> XN in P2 ----
  {
    const int s = tid >> 2, q = tid & 3;
    const float* XP = (const float*)P1;
    const float4* pg = (const float4*)(gam + q * 16);
    const float4* pb = (const float4*)(bet + q * 16);
    float4 g0 = pg[0], g1 = pg[1], g2 = pg[2], g3 = pg[3];
    float4 b0v = pb[0], b1 = pb[1], b2 = pb[2], b3 = pb[3];
    float gr[16] = {g0.x, g0.y, g0.z, g0.w, g1.x, g1.y, g1.z, g1.w,
                    g2.x, g2.y, g2.z, g2.w, g3.x, g3.y, g3.z, g3.w};
    float br[16] = {b0v.x, b0v.y, b0v.z, b0v.w, b1.x, b1.y, b1.z, b1.w,
                    b2.x, b2.y, b2.z, b2.w, b3.x, b3.y, b3.z, b3.w};
    const float4* pr = (const float4*)&XP[s * 68 + q * 16];
    float4 x0 = pr[0], x1 = pr[1], x2 = pr[2], x3 = pr[3];
    float xr[16] = {x0.x, x0.y, x0.z, x0.w, x1.x, x1.y, x1.z, x1.w,
                    x2.x, x2.y, x2.z, x2.w, x3.x, x3.y, x3.z, x3.w};
    float sum = 0.f, ss = 0.f;
#pragma unroll
    for (int i = 0; i < 16; i++) { sum += xr[i]; ss = fmaf(xr[i], xr[i], ss); }
    sum += __shfl_xor(sum, 1); ss += __shfl_xor(ss, 1);
    sum += __shfl_xor(sum, 2); ss += __shfl_xor(ss, 2);
    const float mu = sum * 0.015625f;
    const float rs = __builtin_amdgcn_rsqf(ss * 0.015625f - mu * mu + 1e-5f);
    bfrag o0, o1;
#pragma unroll
    for (int i = 0; i < 8; i++) o0[i] = (__bf16)((xr[i] - mu) * rs * gr[i] + br[i]);
#pragma unroll
    for (int i = 0; i < 8; i++) o1[i] = (__bf16)((xr[8 + i] - mu) * rs * gr[8 + i] + br[8 + i]);
    *(bfrag*)&P2[s * 72 + q * 16] = o0;
    *(bfrag*)&P2[s * 72 + q * 16 + 8] = o1;
  }
  __syncthreads();   // #1: XN visible to all waves

  // ---- D: QKV. XF frags then Q/K/V ----
  bfrag XF[4][2];
#pragma unroll
  for (int st = 0; st < 4; st++) {
    XF[st][0] = *(const bfrag*)&P2[(st * 16 + m) * 72 + g * 8];
    XF[st][1] = *(const bfrag*)&P2[(st * 16 + m) * 72 + 32 + g * 8];
  }
  __syncthreads();   // #2: XF loaded everywhere; V may now overwrite P2

  {
    // Q and K tiles, transposed (A=W rows n, B=XN): wave w -> n-tiles w, w+4
    // Q (i==0) pre-scaled by SCL2 so stage E is exp2(sc) directly.
#pragma unroll
    for (int i = 0; i < 2; i++) {
      const int nt = w + 4 * i;                       // 0..7 (Q: 0-3, K: 4-7)
      bfrag AW0 = cvt8(qkvw + (size_t)(nt * 16 + m) * 64 + g * 8);
      bfrag AW1 = cvt8(qkvw + (size_t)(nt * 16 + m) * 64 + 32 + g * 8);
      float4 qb4 = *(const float4*)(qkvb + nt * 16 + g * 4);
      const float qs = (i == 0) ? SCL2 : 1.0f;
      const float qbx = qb4.x * qs, qby = qb4.y * qs;
      const float qbz = qb4.z * qs, qbw = qb4.w * qs;
#pragma unroll
      for (int st = 0; st < 4; st++) {
        f32x4 c = {0.f, 0.f, 0.f, 0.f};
        c = MFMA16(AW0, XF[st][0], c);                // C: col=s, rows=n
        c = MFMA16(AW1, XF[st][1], c);
        bf4 pk;
        pk[0] = (__bf16)fmaf(c[0], qs, qbx); pk[1] = (__bf16)fmaf(c[1], qs, qby);
        pk[2] = (__bf16)fmaf(c[2], qs, qbz); pk[3] = (__bf16)fmaf(c[3], qs, qbw);
        *(bf4*)&P1[(st * 16 + m) * 136 + nt * 16 + g * 4] = pk;
      }
    }
    // V (A=XN rows s, B=W cols n): wave w -> v^T rows 16w..16w+15
    {
      const int n = 128 + w * 16 + m;
      bfrag BV0 = cvt8(qkvw + (size_t)n * 64 + g * 8);
      bfrag BV1 = cvt8(qkvw + (size_t)n * 64 + 32 + g * 8);
      const float vb = qkvb[n];
#pragma unroll
      for (int st = 0; st < 4; st++) {
        f32x4 c = {0.f, 0.f, 0.f, 0.f};
        c = MFMA16(XF[st][0], BV0, c);                // C: col=v-row, rows=s
        c = MFMA16(XF[st][1], BV1, c);
        bf4 pk;
#pragma unroll
        for (int r = 0; r < 4; r++) pk[r] = (__bf16)(c[r] + vb);
        *(bf4*)&P2[(w * 16 + m) * 72 + st * 16 + g * 4] = pk;
      }
    }
  }
  // NO barrier: stage E of wave w consumes only wave-w-produced Q/K/V
  // (Q cols 16w.., K cols 64+16w.., v rows 16w..); same-wave DS ordering.

  // ---- E: attention, heads h = 2w, 2w+1 (wave-local). S^T = K*Q^T with
  //      bias*log2e accumulator init; P bounced through the wave's own
  //      consumed-v rows; AO overwrites own heads' K cols (KA in regs). ----
  const bfrag ZF  = bsplat(0.f);
  const bfrag ONE = bsplat(1.f);
  const int rowoff = (16 * w + m) * 72;     // wave-private scratch row (s'=m)

  bfrag VA[2][2];   // [hl][kf] — fully hoisted before scratch overlays v rows
#pragma unroll
  for (int hl = 0; hl < 2; hl++)
#pragma unroll
    for (int kf = 0; kf < 2; kf++)
      VA[hl][kf] = (m < 8)
          ? *(const bfrag*)&P2[(16 * w + 8 * hl + m) * 72 + kf * 32 + g * 8]
          : ((m == 8) ? ONE : ZF);

#pragma unroll
  for (int hl = 0; hl < 2; hl++) {
    const int h8 = 16 * w + 8 * hl;       // this wave's head col base (Q; K +64)
    bfrag KA[4];
#pragma unroll
    for (int tt = 0; tt < 4; tt++)
      KA[tt] = (lane < 16) ? *(const bfrag*)&P1[(tt * 16 + m) * 136 + 64 + h8] : ZF;
#pragma unroll
    for (int st = 0; st < 4; st++) {
      // bias tile in C-fragment layout, pre-scaled by log2(e)
      f32x4 binit[4];
#pragma unroll
      for (int tt = 0; tt < 4; tt++) {
        float4 bv = *(const float4*)(biasg + (size_t)(st * 16 + m) * 64 + tt * 16 + g * 4);
        binit[tt][0] = bv.x * LN2I; binit[tt][1] = bv.y * LN2I;
        binit[tt][2] = bv.z * LN2I; binit[tt][3] = bv.w * LN2I;
      }
      bfrag QB = (lane < 16) ? *(const bfrag*)&P1[(st * 16 + m) * 136 + h8] : ZF;
      f32x4 sc[4];
#pragma unroll
      for (int tt = 0; tt < 4; tt++)
        sc[tt] = MFMA16(KA[tt], QB, binit[tt]);   // col=s, rows=t
#pragma unroll
      for (int tt = 0; tt < 4; tt++) {
        bf4 pr;
        pr[0] = (__bf16)__builtin_amdgcn_exp2f(sc[tt][0]);
        pr[1] = (__bf16)__builtin_amdgcn_exp2f(sc[tt][1]);
        pr[2] = (__bf16)__builtin_amdgcn_exp2f(sc[tt][2]);
        pr[3] = (__bf16)__builtin_amdgcn_exp2f(sc[tt][3]);
        *(bf4*)&P2[rowoff + tt * 16 + g * 4] = pr;
      }
      bfrag PB0 = *(const bfrag*)&P2[rowoff + g * 8];
      bfrag PB1 = *(const bfrag*)&P2[rowoff + 32 + g * 8];
      f32x4 oo = {0.f, 0.f, 0.f, 0.f};
      oo = MFMA16(VA[hl][0], PB0, oo);      // O^T: col=s, rows=d; row 8 = sum
      oo = MFMA16(VA[hl][1], PB1, oo);
      const float rsum = __builtin_amdgcn_rcpf(__shfl(oo[0], 32 + m));
      bf4 ov;
#pragma unroll
      for (int r = 0; r < 4; r++) ov[r] = (__bf16)(oo[r] * rsum);
      // AO[s][h*8+d] overwrites this head's K columns (KA is in registers)
      if (g < 2) *(bf4*)&P1[(st * 16 + m) * 136 + 64 + h8 + g * 4] = ov;
    }
  }
  __syncthreads();   // #3: AO complete (cross-wave consumption in F)

  // ---- F: O[s][e] = AO * out_w^T + residual; AO in cols 64..127 ----
  {
    bfrag A0 = *(const bfrag*)&P1[(w * 16 + m) * 136 + 64 + g * 8];
    bfrag A1 = *(const bfrag*)&P1[(w * 16 + m) * 136 + 96 + g * 8];
    const int sbase = w * 16 + g * 4;
    const size_t xoff = (size_t)b * 4096;
#pragma unroll
    for (int et = 0; et < 4; et++) {
      const int e = et * 16 + m;
      bfrag BW0 = cvt8(outw + (size_t)e * 64 + g * 8);
      bfrag BW1 = cvt8(outw + (size_t)e * 64 + 32 + g * 8);
      const float ob = outb[e];
      float4 pv = *(const float4*)(posg + (size_t)e * 64 + sbase);
      f32x4 c = {0.f, 0.f, 0.f, 0.f};
      c = MFMA16(A0, BW0, c);               // col=e, rows=s (4 consec/lane)
      c = MFMA16(A1, BW1, c);
      float4 xv = *(const float4*)(xg + xoff + (size_t)e * 64 + sbase);
      float4 o;
      o.x = c[0] + ob + xv.x + pv.x;
      o.y = c[1] + ob + xv.y + pv.y;
      o.z = c[2] + ob + xv.z + pv.z;
      o.w = c[3] + ob + xv.w + pv.w;
      *(float4*)(outg + xoff + (size_t)e * 64 + sbase) = o;
    }
  }
}

extern "C" void kernel_launch(void* const* d_in, const int* in_sizes, int n_in,
                              void* d_out, int out_size, void* d_ws, size_t ws_size,
                              hipStream_t stream) {
  const float* xg   = (const float*)d_in[0];
  const float* pos  = (const float*)d_in[1];
  const float* gam  = (const float*)d_in[2];
  const float* bet  = (const float*)d_in[3];
  const float* qkvw = (const float*)d_in[4];
  const float* qkvb = (const float*)d_in[5];
  const float* outw = (const float*)d_in[6];
  const float* outb = (const float*)d_in[7];
  const float* cb   = (const float*)d_in[8];
  float* out = (float*)d_out;
  const int B = in_sizes[0] / (64 * 64);   // 4096
  hipLaunchKernelGGL(chess_attn_kernel, dim3(B), dim3(256), 0, stream,
                     xg, pos, gam, bet, qkvw, qkvb, outw, outb, cb, out);
}

// Round 10
// 184.319 us; speedup vs baseline: 1.5713x; 1.2496x over previous
//
#include <hip/hip_runtime.h>
#include <stdint.h>

// ChessMultiStageAttention: B=4096 fused blocks of (pos-add, LN, QKV, 8-head
// attention S=64 D=8 with chess bias, out-proj, residual). f32 I/O, bf16 MFMA
// (16x16x32_bf16) with f32 accum.
//
// Round-14: round-11 champion (94 us/dispatch, best harness 186.6) + ONE
// delta: stages A+B fused. The f32 x+pos LDS staging existed only to move
// data from the coalesced (lane=c) load layout to the (s=tid>>2, q=tid&3) LN
// layout. Instead each LN thread loads its 16 c-values DIRECTLY from global:
// x[b][q*16+i][s] — the 16 same-q lanes of a wave cover full contiguous 64B
// lines per instruction (perfect coalescing), i-stride 256B folds into the
// load-instruction offset field. Deletes 32 ds_write_b32 + 8 ds_read_b128
// per thread and one global->LDS->reg hop from the critical path; LN math
// and all downstream stages bit-identical. P1 never holds f32.
//
// Rationale from r12/r13: per-wave lifetime is invariant under work changes
// (latency-structure-bound); occupancy raises don't pay (falsified 3x); the
// winning direction is shortening the per-wave chain at constant
// amortization.
//
// Kept from rounds 8-11: bias folded into score-MFMA accumulator (C-layout ==
// bias tile layout, pre-scaled by log2e); softmax scale folded into Q at the
// stage-D store; wave-local heads {2w,2w+1} (no barrier between QKV and
// attention); KA register cache per hl; P bounced through the wave's own
// consumed v^T rows (buffer keyed by item); AO overwrites own heads' K cols.
//
// MFMA layouts (m89-verified):
//   A: lane m=lane&15 holds row m, k=(lane>>4)*8+j (k-contiguous 16B)
//   B: lane holds col n=lane&15, k=(lane>>4)*8+j
//   C/D: col=lane&15, row=(lane>>4)*4+reg
//
// LDS per item (26624 B; x2 = 53248 B -> 3 WG/CU):
//   P1 [64][136] bf16: (D) Q cols 0..63 (pre-scaled), K cols 64..127 /
//       (E) AO overwrites own heads' K cols
//   P2 [64][72]  bf16: (B) x_norm -> XF regs / (D-E) v^T [(h,d)][t] /
//       (E) wave w's v rows 16w..16w+15 (both items) = 2 P-scratch buffers

typedef __attribute__((ext_vector_type(8))) __bf16 bfrag;
typedef __attribute__((ext_vector_type(4))) __bf16 bf4;
typedef __attribute__((ext_vector_type(4))) float f32x4;

#define MFMA16(a, b, c) __builtin_amdgcn_mfma_f32_16x16x32_bf16((a), (b), (c), 0, 0, 0)

static __device__ __forceinline__ bfrag bsplat(float v) {
  bfrag z;
#pragma unroll
  for (int i = 0; i < 8; i++) z[i] = (__bf16)v;
  return z;
}

static __device__ __forceinline__ bfrag cvt8(const float* __restrict__ p) {
  float4 a = *(const float4*)p, b = *(const float4*)(p + 4);
  bfrag r;
  r[0] = (__bf16)a.x; r[1] = (__bf16)a.y; r[2] = (__bf16)a.z; r[3] = (__bf16)a.w;
  r[4] = (__bf16)b.x; r[5] = (__bf16)b.y; r[6] = (__bf16)b.z; r[7] = (__bf16)b.w;
  return r;
}

__global__ __launch_bounds__(256, 3) void chess_attn_kernel(
    const float* __restrict__ xg,    const float* __restrict__ posg,
    const float* __restrict__ gam,   const float* __restrict__ bet,
    const float* __restrict__ qkvw,  const float* __restrict__ qkvb,
    const float* __restrict__ outw,  const float* __restrict__ outb,
    const float* __restrict__ biasg, float* __restrict__ outg) {
  __shared__ __attribute__((aligned(16))) __bf16 P1[2][64 * 136];  // 2x17408 B
  __shared__ __attribute__((aligned(16))) __bf16 P2[2][64 * 72];   // 2x 9216 B

  const int tid = threadIdx.x, lane = tid & 63, w = tid >> 6;
  const int m = lane & 15, g = lane >> 4;
  const int b0 = blockIdx.x * 2;
  const float LN2I = 1.4426950408889634f;                        // log2(e)
  const float SCL2 = 0.35355339059327373f * 1.4426950408889634f; // (1/sqrt8)*log2e

  // ---- A+B fused: direct global loads in LN layout + LayerNorm -> P2 ----
  {
    const int s = tid >> 2, q = tid & 3;
    const float4* pg = (const float4*)(gam + q * 16);
    const float4* pb = (const float4*)(bet + q * 16);
    float4 g0 = pg[0], g1 = pg[1], g2 = pg[2], g3 = pg[3];
    float4 b0v = pb[0], b1 = pb[1], b2 = pb[2], b3 = pb[3];
    float gr[16] = {g0.x, g0.y, g0.z, g0.w, g1.x, g1.y, g1.z, g1.w,
                    g2.x, g2.y, g2.z, g2.w, g3.x, g3.y, g3.z, g3.w};
    float br[16] = {b0v.x, b0v.y, b0v.z, b0v.w, b1.x, b1.y, b1.z, b1.w,
                    b2.x, b2.y, b2.z, b2.w, b3.x, b3.y, b3.z, b3.w};
    // pos row-chunk for (s,q): pos[c=q*16+i][s]; shared across both items.
    const float* pp = posg + (size_t)(q * 16) * 64 + s;
    float pv[16];
#pragma unroll
    for (int i = 0; i < 16; i++) pv[i] = pp[i * 64];
#pragma unroll
    for (int it = 0; it < 2; it++) {
      const float* xb = xg + (size_t)(b0 + it) * 4096 + (size_t)(q * 16) * 64 + s;
      float xr[16];
#pragma unroll
      for (int i = 0; i < 16; i++) xr[i] = xb[i * 64] + pv[i];
      float sum = 0.f, ss = 0.f;
#pragma unroll
      for (int i = 0; i < 16; i++) { sum += xr[i]; ss = fmaf(xr[i], xr[i], ss); }
      sum += __shfl_xor(sum, 1); ss += __shfl_xor(ss, 1);
      sum += __shfl_xor(sum, 2); ss += __shfl_xor(ss, 2);
      const float mu = sum * 0.015625f;
      const float rs = __builtin_amdgcn_rsqf(ss * 0.015625f - mu * mu + 1e-5f);
      bfrag o0, o1;
#pragma unroll
      for (int i = 0; i < 8; i++) o0[i] = (__bf16)((xr[i] - mu) * rs * gr[i] + br[i]);
#pragma unroll
      for (int i = 0; i < 8; i++) o1[i] = (__bf16)((xr[8 + i] - mu) * rs * gr[8 + i] + br[8 + i]);
      *(bfrag*)&P2[it][s * 72 + q * 16] = o0;
      *(bfrag*)&P2[it][s * 72 + q * 16 + 8] = o1;
    }
  }
  __syncthreads();   // #1: XN visible to all waves

  // ---- D: QKV. XF frags (both items) then Q/K/V with shared weight loads ----
  bfrag XF[2][4][2];
#pragma unroll
  for (int it = 0; it < 2; it++)
#pragma unroll
    for (int st = 0; st < 4; st++) {
      XF[it][st][0] = *(const bfrag*)&P2[it][(st * 16 + m) * 72 + g * 8];
      XF[it][st][1] = *(const bfrag*)&P2[it][(st * 16 + m) * 72 + 32 + g * 8];
    }
  __syncthreads();   // #2: XF loaded everywhere; V may now overwrite P2

  {
    // Q and K tiles, transposed (A=W rows n, B=XN): wave w -> n-tiles w, w+4
    // Q (i==0) pre-scaled by SCL2 so stage E is exp2(sc) directly.
#pragma unroll
    for (int i = 0; i < 2; i++) {
      const int nt = w + 4 * i;                       // 0..7 (Q: 0-3, K: 4-7)
      bfrag AW0 = cvt8(qkvw + (size_t)(nt * 16 + m) * 64 + g * 8);
      bfrag AW1 = cvt8(qkvw + (size_t)(nt * 16 + m) * 64 + 32 + g * 8);
      float4 qb4 = *(const float4*)(qkvb + nt * 16 + g * 4);
      const float qs = (i == 0) ? SCL2 : 1.0f;
      const float qbx = qb4.x * qs, qby = qb4.y * qs;
      const float qbz = qb4.z * qs, qbw = qb4.w * qs;
#pragma unroll
      for (int it = 0; it < 2; it++)
#pragma unroll
        for (int st = 0; st < 4; st++) {
          f32x4 c = {0.f, 0.f, 0.f, 0.f};
          c = MFMA16(AW0, XF[it][st][0], c);          // C: col=s, rows=n
          c = MFMA16(AW1, XF[it][st][1], c);
          bf4 pk;
          pk[0] = (__bf16)fmaf(c[0], qs, qbx); pk[1] = (__bf16)fmaf(c[1], qs, qby);
          pk[2] = (__bf16)fmaf(c[2], qs, qbz); pk[3] = (__bf16)fmaf(c[3], qs, qbw);
          *(bf4*)&P1[it][(st * 16 + m) * 136 + nt * 16 + g * 4] = pk;
        }
    }
    // V (A=XN rows s, B=W cols n): wave w -> v^T rows 16w..16w+15
    {
      const int n = 128 + w * 16 + m;
      bfrag BV0 = cvt8(qkvw + (size_t)n * 64 + g * 8);
      bfrag BV1 = cvt8(qkvw + (size_t)n * 64 + 32 + g * 8);
      const float vb = qkvb[n];
#pragma unroll
      for (int it = 0; it < 2; it++)
#pragma unroll
        for (int st = 0; st < 4; st++) {
          f32x4 c = {0.f, 0.f, 0.f, 0.f};
          c = MFMA16(XF[it][st][0], BV0, c);          // C: col=v-row, rows=s
          c = MFMA16(XF[it][st][1], BV1, c);
          bf4 pk;
#pragma unroll
          for (int r = 0; r < 4; r++) pk[r] = (__bf16)(c[r] + vb);
          *(bf4*)&P2[it][(w * 16 + m) * 72 + st * 16 + g * 4] = pk;
        }
    }
  }
  // NO barrier: stage E of wave w consumes only wave-w-produced Q/K/V
  // (Q cols 16w.., K cols 64+16w.., v rows 16w..); same-wave DS ordering.

  // ---- E: attention, heads h = 2w, 2w+1 (wave-local). S^T = K*Q^T with
  //      bias*log2e accumulator init; P bounced through the wave's own
  //      consumed-v rows (buffer keyed by combo item); AO overwrites own
  //      heads' K cols (KA already cached in regs). ----
  const bfrag ZF  = bsplat(0.f);
  const bfrag ONE = bsplat(1.f);
  __bf16* PS = &P2[0][0];
  const int a7 = m & 7;
  // scratch slot for s'=m: buffer b rows (16w + 8b + (m&7)), item-half (m>>3)
  const int rowoffA = (16 * w + a7) * 72 + (m >> 3) * 4608;   // buffer 0 (it=0)
  const int rowoffB = rowoffA + 8 * 72;                       // buffer 1 (it=1)

  bfrag VA[2][2][2];   // [it][hl][kf] — fully hoisted before scratch overlays
#pragma unroll
  for (int it = 0; it < 2; it++)
#pragma unroll
    for (int hl = 0; hl < 2; hl++)
#pragma unroll
      for (int kf = 0; kf < 2; kf++)
        VA[it][hl][kf] = (m < 8)
            ? *(const bfrag*)&P2[it][(16 * w + 8 * hl + m) * 72 + kf * 32 + g * 8]
            : ((m == 8) ? ONE : ZF);

#pragma unroll
  for (int hl = 0; hl < 2; hl++) {
    const int h8 = 16 * w + 8 * hl;       // this wave's head col base (Q; K +64)
    bfrag KA[2][4];
#pragma unroll
    for (int it = 0; it < 2; it++)
#pragma unroll
      for (int tt = 0; tt < 4; tt++)
        KA[it][tt] = (lane < 16) ? *(const bfrag*)&P1[it][(tt * 16 + m) * 136 + 64 + h8] : ZF;
#pragma unroll
    for (int st = 0; st < 4; st++) {
      // bias tile in C-fragment layout, pre-scaled by log2(e); shared by combos
      f32x4 binit[4];
#pragma unroll
      for (int tt = 0; tt < 4; tt++) {
        float4 bv = *(const float4*)(biasg + (size_t)(st * 16 + m) * 64 + tt * 16 + g * 4);
        binit[tt][0] = bv.x * LN2I; binit[tt][1] = bv.y * LN2I;
        binit[tt][2] = bv.z * LN2I; binit[tt][3] = bv.w * LN2I;
      }
#pragma unroll
      for (int it = 0; it < 2; it++) {
        const int rowoff = it ? rowoffB : rowoffA;
        bfrag QB = (lane < 16) ? *(const bfrag*)&P1[it][(st * 16 + m) * 136 + h8] : ZF;
        f32x4 sc[4];
#pragma unroll
        for (int tt = 0; tt < 4; tt++)
          sc[tt] = MFMA16(KA[it][tt], QB, binit[tt]);   // col=s, rows=t
#pragma unroll
        for (int tt = 0; tt < 4; tt++) {
          bf4 pr;
          pr[0] = (__bf16)__builtin_amdgcn_exp2f(sc[tt][0]);
          pr[1] = (__bf16)__builtin_amdgcn_exp2f(sc[tt][1]);
          pr[2] = (__bf16)__builtin_amdgcn_exp2f(sc[tt][2]);
          pr[3] = (__bf16)__builtin_amdgcn_exp2f(sc[tt][3]);
          *(bf4*)&PS[rowoff + tt * 16 + g * 4] = pr;
        }
        bfrag PB0 = *(const bfrag*)&PS[rowoff + g * 8];
        bfrag PB1 = *(const bfrag*)&PS[rowoff + 32 + g * 8];
        f32x4 oo = {0.f, 0.f, 0.f, 0.f};
        oo = MFMA16(VA[it][hl][0], PB0, oo);   // O^T: col=s, rows=d; row 8 = sum
        oo = MFMA16(VA[it][hl][1], PB1, oo);
        const float rsum = __builtin_amdgcn_rcpf(__shfl(oo[0], 32 + m));
        bf4 ov;
#pragma unroll
        for (int r = 0; r < 4; r++) ov[r] = (__bf16)(oo[r] * rsum);
        // AO[s][h*8+d] overwrites this head's K columns (KA is in registers)
        if (g < 2) *(bf4*)&P1[it][(st * 16 + m) * 136 + 64 + h8 + g * 4] = ov;
      }
    }
  }
  __syncthreads();   // #3: AO complete (cross-wave consumption in F)

  // ---- F: O[s][e] = AO * out_w^T + residual; AO in cols 64..127 ----
  {
    bfrag A0[2], A1[2];
#pragma unroll
    for (int it = 0; it < 2; it++) {
      A0[it] = *(const bfrag*)&P1[it][(w * 16 + m) * 136 + 64 + g * 8];
      A1[it] = *(const bfrag*)&P1[it][(w * 16 + m) * 136 + 96 + g * 8];
    }
    const int sbase = w * 16 + g * 4;
#pragma unroll
    for (int et = 0; et < 4; et++) {
      const int e = et * 16 + m;
      bfrag BW0 = cvt8(outw + (size_t)e * 64 + g * 8);
      bfrag BW1 = cvt8(outw + (size_t)e * 64 + 32 + g * 8);
      const float ob = outb[e];
      float4 pv = *(const float4*)(posg + (size_t)e * 64 + sbase);
#pragma unroll
      for (int it = 0; it < 2; it++) {
        const size_t xoff = (size_t)(b0 + it) * 4096;
        f32x4 c = {0.f, 0.f, 0.f, 0.f};
        c = MFMA16(A0[it], BW0, c);           // col=e, rows=s (4 consec/lane)
        c = MFMA16(A1[it], BW1, c);
        float4 xv = *(const float4*)(xg + xoff + (size_t)e * 64 + sbase);
        float4 o;
        o.x = c[0] + ob + xv.x + pv.x;
        o.y = c[1] + ob + xv.y + pv.y;
        o.z = c[2] + ob + xv.z + pv.z;
        o.w = c[3] + ob + xv.w + pv.w;
        *(float4*)(outg + xoff + (size_t)e * 64 + sbase) = o;
      }
    }
  }
}

extern "C" void kernel_launch(void* const* d_in, const int* in_sizes, int n_in,
                              void* d_out, int out_size, void* d_ws, size_t ws_size,
                              hipStream_t stream) {
  const float* xg   = (const float*)d_in[0];
  const float* pos  = (const float*)d_in[1];
  const float* gam  = (const float*)d_in[2];
  const float* bet  = (const float*)d_in[3];
  const float* qkvw = (const float*)d_in[4];
  const float* qkvb = (const float*)d_in[5];
  const float* outw = (const float*)d_in[6];
  const float* outb = (const float*)d_in[7];
  const float* cb   = (const float*)d_in[8];
  float* out = (float*)d_out;
  const int B = in_sizes[0] / (64 * 64);   // 4096
  hipLaunchKernelGGL(chess_attn_kernel, dim3(B / 2), dim3(256), 0, stream,
                     xg, pos, gam, bet, qkvw, qkvb, outw, outb, cb, out);
}

// Round 11
// 182.981 us; speedup vs baseline: 1.5828x; 1.0073x over previous
//
#include <hip/hip_runtime.h>
#include <stdint.h>

// ChessMultiStageAttention: B=4096 fused blocks of (pos-add, LN, QKV, 8-head
// attention S=64 D=8 with chess bias, out-proj, residual). f32 I/O, bf16 MFMA
// (16x16x32_bf16) with f32 accum.
//
// Round-15: round-14 champion (91.5 us/dispatch, harness 184.3) + ONE delta:
// stage E software-pipelined by one combo. Combo c's {PB read, PV MFMA, rsum,
// AO store} is deferred into iteration c+1: the PB ds_read issues right after
// c+1's QK MFMAs and its ~120-cycle LDS latency hides under c+1's exp2/pack
// block, instead of being exposed immediately before the PV consumer (16x per
// wave). Scratch buffers already alternate by combo parity (== it), so
// write(c) clobbers a buffer whose deferred read completed in iteration c-1 —
// anti-dep distance preserved, zero extra LDS. Math bit-identical, order only.
// Epilogue drains combo 15.
//
// Kept from rounds 8-14: A+B fused (direct global loads in LN layout, no f32
// staging); bias folded into score-MFMA accumulator (C-layout == bias tile
// layout, pre-scaled by log2e); softmax scale folded into Q at the stage-D
// store; wave-local heads {2w,2w+1} (no barrier between QKV and attention);
// KA register cache per hl; P bounced through the wave's own consumed v^T
// rows (buffer keyed by combo parity); AO overwrites own heads' K cols.
//
// MFMA layouts (m89-verified):
//   A: lane m=lane&15 holds row m, k=(lane>>4)*8+j (k-contiguous 16B)
//   B: lane holds col n=lane&15, k=(lane>>4)*8+j
//   C/D: col=lane&15, row=(lane>>4)*4+reg
//
// LDS per item (26624 B; x2 = 53248 B -> 3 WG/CU):
//   P1 [64][136] bf16: (D) Q cols 0..63 (pre-scaled), K cols 64..127 /
//       (E) AO overwrites own heads' K cols
//   P2 [64][72]  bf16: (B) x_norm -> XF regs / (D-E) v^T [(h,d)][t] /
//       (E) wave w's v rows 16w..16w+15 (both items) = 2 P-scratch buffers

typedef __attribute__((ext_vector_type(8))) __bf16 bfrag;
typedef __attribute__((ext_vector_type(4))) __bf16 bf4;
typedef __attribute__((ext_vector_type(4))) float f32x4;

#define MFMA16(a, b, c) __builtin_amdgcn_mfma_f32_16x16x32_bf16((a), (b), (c), 0, 0, 0)

static __device__ __forceinline__ bfrag bsplat(float v) {
  bfrag z;
#pragma unroll
  for (int i = 0; i < 8; i++) z[i] = (__bf16)v;
  return z;
}

static __device__ __forceinline__ bfrag cvt8(const float* __restrict__ p) {
  float4 a = *(const float4*)p, b = *(const float4*)(p + 4);
  bfrag r;
  r[0] = (__bf16)a.x; r[1] = (__bf16)a.y; r[2] = (__bf16)a.z; r[3] = (__bf16)a.w;
  r[4] = (__bf16)b.x; r[5] = (__bf16)b.y; r[6] = (__bf16)b.z; r[7] = (__bf16)b.w;
  return r;
}

__global__ __launch_bounds__(256, 3) void chess_attn_kernel(
    const float* __restrict__ xg,    const float* __restrict__ posg,
    const float* __restrict__ gam,   const float* __restrict__ bet,
    const float* __restrict__ qkvw,  const float* __restrict__ qkvb,
    const float* __restrict__ outw,  const float* __restrict__ outb,
    const float* __restrict__ biasg, float* __restrict__ outg) {
  __shared__ __attribute__((aligned(16))) __bf16 P1[2][64 * 136];  // 2x17408 B
  __shared__ __attribute__((aligned(16))) __bf16 P2[2][64 * 72];   // 2x 9216 B

  const int tid = threadIdx.x, lane = tid & 63, w = tid >> 6;
  const int m = lane & 15, g = lane >> 4;
  const int b0 = blockIdx.x * 2;
  const float LN2I = 1.4426950408889634f;                        // log2(e)
  const float SCL2 = 0.35355339059327373f * 1.4426950408889634f; // (1/sqrt8)*log2e

  // ---- A+B fused: direct global loads in LN layout + LayerNorm -> P2 ----
  {
    const int s = tid >> 2, q = tid & 3;
    const float4* pg = (const float4*)(gam + q * 16);
    const float4* pb = (const float4*)(bet + q * 16);
    float4 g0 = pg[0], g1 = pg[1], g2 = pg[2], g3 = pg[3];
    float4 b0v = pb[0], b1 = pb[1], b2 = pb[2], b3 = pb[3];
    float gr[16] = {g0.x, g0.y, g0.z, g0.w, g1.x, g1.y, g1.z, g1.w,
                    g2.x, g2.y, g2.z, g2.w, g3.x, g3.y, g3.z, g3.w};
    float br[16] = {b0v.x, b0v.y, b0v.z, b0v.w, b1.x, b1.y, b1.z, b1.w,
                    b2.x, b2.y, b2.z, b2.w, b3.x, b3.y, b3.z, b3.w};
    // pos row-chunk for (s,q): pos[c=q*16+i][s]; shared across both items.
    const float* pp = posg + (size_t)(q * 16) * 64 + s;
    float pv[16];
#pragma unroll
    for (int i = 0; i < 16; i++) pv[i] = pp[i * 64];
#pragma unroll
    for (int it = 0; it < 2; it++) {
      const float* xb = xg + (size_t)(b0 + it) * 4096 + (size_t)(q * 16) * 64 + s;
      float xr[16];
#pragma unroll
      for (int i = 0; i < 16; i++) xr[i] = xb[i * 64] + pv[i];
      float sum = 0.f, ss = 0.f;
#pragma unroll
      for (int i = 0; i < 16; i++) { sum += xr[i]; ss = fmaf(xr[i], xr[i], ss); }
      sum += __shfl_xor(sum, 1); ss += __shfl_xor(ss, 1);
      sum += __shfl_xor(sum, 2); ss += __shfl_xor(ss, 2);
      const float mu = sum * 0.015625f;
      const float rs = __builtin_amdgcn_rsqf(ss * 0.015625f - mu * mu + 1e-5f);
      bfrag o0, o1;
#pragma unroll
      for (int i = 0; i < 8; i++) o0[i] = (__bf16)((xr[i] - mu) * rs * gr[i] + br[i]);
#pragma unroll
      for (int i = 0; i < 8; i++) o1[i] = (__bf16)((xr[8 + i] - mu) * rs * gr[8 + i] + br[8 + i]);
      *(bfrag*)&P2[it][s * 72 + q * 16] = o0;
      *(bfrag*)&P2[it][s * 72 + q * 16 + 8] = o1;
    }
  }
  __syncthreads();   // #1: XN visible to all waves

  // ---- D: QKV. XF frags (both items) then Q/K/V with shared weight loads ----
  bfrag XF[2][4][2];
#pragma unroll
  for (int it = 0; it < 2; it++)
#pragma unroll
    for (int st = 0; st < 4; st++) {
      XF[it][st][0] = *(const bfrag*)&P2[it][(st * 16 + m) * 72 + g * 8];
      XF[it][st][1] = *(const bfrag*)&P2[it][(st * 16 + m) * 72 + 32 + g * 8];
    }
  __syncthreads();   // #2: XF loaded everywhere; V may now overwrite P2

  {
    // Q and K tiles, transposed (A=W rows n, B=XN): wave w -> n-tiles w, w+4
    // Q (i==0) pre-scaled by SCL2 so stage E is exp2(sc) directly.
#pragma unroll
    for (int i = 0; i < 2; i++) {
      const int nt = w + 4 * i;                       // 0..7 (Q: 0-3, K: 4-7)
      bfrag AW0 = cvt8(qkvw + (size_t)(nt * 16 + m) * 64 + g * 8);
      bfrag AW1 = cvt8(qkvw + (size_t)(nt * 16 + m) * 64 + 32 + g * 8);
      float4 qb4 = *(const float4*)(qkvb + nt * 16 + g * 4);
      const float qs = (i == 0) ? SCL2 : 1.0f;
      const float qbx = qb4.x * qs, qby = qb4.y * qs;
      const float qbz = qb4.z * qs, qbw = qb4.w * qs;
#pragma unroll
      for (int it = 0; it < 2; it++)
#pragma unroll
        for (int st = 0; st < 4; st++) {
          f32x4 c = {0.f, 0.f, 0.f, 0.f};
          c = MFMA16(AW0, XF[it][st][0], c);          // C: col=s, rows=n
          c = MFMA16(AW1, XF[it][st][1], c);
          bf4 pk;
          pk[0] = (__bf16)fmaf(c[0], qs, qbx); pk[1] = (__bf16)fmaf(c[1], qs, qby);
          pk[2] = (__bf16)fmaf(c[2], qs, qbz); pk[3] = (__bf16)fmaf(c[3], qs, qbw);
          *(bf4*)&P1[it][(st * 16 + m) * 136 + nt * 16 + g * 4] = pk;
        }
    }
    // V (A=XN rows s, B=W cols n): wave w -> v^T rows 16w..16w+15
    {
      const int n = 128 + w * 16 + m;
      bfrag BV0 = cvt8(qkvw + (size_t)n * 64 + g * 8);
      bfrag BV1 = cvt8(qkvw + (size_t)n * 64 + 32 + g * 8);
      const float vb = qkvb[n];
#pragma unroll
      for (int it = 0; it < 2; it++)
#pragma unroll
        for (int st = 0; st < 4; st++) {
          f32x4 c = {0.f, 0.f, 0.f, 0.f};
          c = MFMA16(XF[it][st][0], BV0, c);          // C: col=v-row, rows=s
          c = MFMA16(XF[it][st][1], BV1, c);
          bf4 pk;
#pragma unroll
          for (int r = 0; r < 4; r++) pk[r] = (__bf16)(c[r] + vb);
          *(bf4*)&P2[it][(w * 16 + m) * 72 + st * 16 + g * 4] = pk;
        }
    }
  }
  // NO barrier: stage E of wave w consumes only wave-w-produced Q/K/V
  // (Q cols 16w.., K cols 64+16w.., v rows 16w..); same-wave DS ordering.

  // ---- E: attention, heads h = 2w, 2w+1 (wave-local). S^T = K*Q^T with
  //      bias*log2e accumulator init; P bounced through the wave's own
  //      consumed-v rows. SOFTWARE-PIPELINED: combo c's PB read issues under
  //      combo c+1's exp2 block; PV/rsum/AO-store of c run in iteration c+1.
  //      Buffers keyed by combo parity (== it): write(c) clobbers the buffer
  //      whose deferred read completed in iteration c-1. ----
  const bfrag ZF  = bsplat(0.f);
  const bfrag ONE = bsplat(1.f);
  __bf16* PS = &P2[0][0];
  const int a7 = m & 7;
  // scratch slot for s'=m: buffer b rows (16w + 8b + (m&7)), item-half (m>>3)
  const int rowoffA = (16 * w + a7) * 72 + (m >> 3) * 4608;   // parity 0
  const int rowoffB = rowoffA + 8 * 72;                       // parity 1

  bfrag VA[2][2][2];   // [it][hl][kf] — fully hoisted before scratch overlays
#pragma unroll
  for (int it = 0; it < 2; it++)
#pragma unroll
    for (int hl = 0; hl < 2; hl++)
#pragma unroll
      for (int kf = 0; kf < 2; kf++)
        VA[it][hl][kf] = (m < 8)
            ? *(const bfrag*)&P2[it][(16 * w + 8 * hl + m) * 72 + kf * 32 + g * 8]
            : ((m == 8) ? ONE : ZF);

#pragma unroll
  for (int hl = 0; hl < 2; hl++) {
    const int h8 = 16 * w + 8 * hl;       // this wave's head col base (Q; K +64)
    bfrag KA[2][4];
#pragma unroll
    for (int it = 0; it < 2; it++)
#pragma unroll
      for (int tt = 0; tt < 4; tt++)
        KA[it][tt] = (lane < 16) ? *(const bfrag*)&P1[it][(tt * 16 + m) * 136 + 64 + h8] : ZF;
#pragma unroll
    for (int st = 0; st < 4; st++) {
      // bias tile in C-fragment layout, pre-scaled by log2(e); shared by combos
      f32x4 binit[4];
#pragma unroll
      for (int tt = 0; tt < 4; tt++) {
        float4 bv = *(const float4*)(biasg + (size_t)(st * 16 + m) * 64 + tt * 16 + g * 4);
        binit[tt][0] = bv.x * LN2I; binit[tt][1] = bv.y * LN2I;
        binit[tt][2] = bv.z * LN2I; binit[tt][3] = bv.w * LN2I;
      }
#pragma unroll
      for (int it = 0; it < 2; it++) {
        const int c = hl * 8 + st * 2 + it;           // combo index, compile-time
        const int rowoff = it ? rowoffB : rowoffA;
        // -- current combo: QK^T scores --
        bfrag QB = (lane < 16) ? *(const bfrag*)&P1[it][(st * 16 + m) * 136 + h8] : ZF;
        f32x4 sc[4];
#pragma unroll
        for (int tt = 0; tt < 4; tt++)
          sc[tt] = MFMA16(KA[it][tt], QB, binit[tt]);   // col=s, rows=t
        // -- prev combo: issue PB reads (latency hides under exp2 below) --
        bfrag PB0p = ZF, PB1p = ZF;
        if (c > 0) {
          const int po = ((c - 1) & 1) ? rowoffB : rowoffA;
          PB0p = *(const bfrag*)&PS[po + g * 8];
          PB1p = *(const bfrag*)&PS[po + 32 + g * 8];
        }
        // -- current combo: exp2 + pack + scratch write --
#pragma unroll
        for (int tt = 0; tt < 4; tt++) {
          bf4 pr;
          pr[0] = (__bf16)__builtin_amdgcn_exp2f(sc[tt][0]);
          pr[1] = (__bf16)__builtin_amdgcn_exp2f(sc[tt][1]);
          pr[2] = (__bf16)__builtin_amdgcn_exp2f(sc[tt][2]);
          pr[3] = (__bf16)__builtin_amdgcn_exp2f(sc[tt][3]);
          *(bf4*)&PS[rowoff + tt * 16 + g * 4] = pr;
        }
        // -- prev combo: PV + rsum + AO store --
        if (c > 0) {
          const int pc = c - 1;
          const int pit = pc & 1, pst = (pc >> 1) & 3, phl = pc >> 3;
          const int ph8 = 16 * w + 8 * phl;
          f32x4 oo = {0.f, 0.f, 0.f, 0.f};
          oo = MFMA16(VA[pit][phl][0], PB0p, oo);  // O^T: col=s, rows=d; row8=sum
          oo = MFMA16(VA[pit][phl][1], PB1p, oo);
          const float rsum = __builtin_amdgcn_rcpf(__shfl(oo[0], 32 + m));
          bf4 ov;
#pragma unroll
          for (int r = 0; r < 4; r++) ov[r] = (__bf16)(oo[r] * rsum);
          // AO[s][h*8+d] overwrites prev head's K columns (KA is in registers)
          if (g < 2) *(bf4*)&P1[pit][(pst * 16 + m) * 136 + 64 + ph8 + g * 4] = ov;
        }
      }
    }
  }
  // -- epilogue: drain combo 15 (hl=1, st=3, it=1) --
  {
    bfrag PB0p = *(const bfrag*)&PS[rowoffB + g * 8];
    bfrag PB1p = *(const bfrag*)&PS[rowoffB + 32 + g * 8];
    f32x4 oo = {0.f, 0.f, 0.f, 0.f};
    oo = MFMA16(VA[1][1][0], PB0p, oo);
    oo = MFMA16(VA[1][1][1], PB1p, oo);
    const float rsum = __builtin_amdgcn_rcpf(__shfl(oo[0], 32 + m));
    bf4 ov;
#pragma unroll
    for (int r = 0; r < 4; r++) ov[r] = (__bf16)(oo[r] * rsum);
    if (g < 2) *(bf4*)&P1[1][(3 * 16 + m) * 136 + 64 + (16 * w + 8) + g * 4] = ov;
  }
  __syncthreads();   // #3: AO complete (cross-wave consumption in F)

  // ---- F: O[s][e] = AO * out_w^T + residual; AO in cols 64..127 ----
  {
    bfrag A0[2], A1[2];
#pragma unroll
    for (int it = 0; it < 2; it++) {
      A0[it] = *(const bfrag*)&P1[it][(w * 16 + m) * 136 + 64 + g * 8];
      A1[it] = *(const bfrag*)&P1[it][(w * 16 + m) * 136 + 96 + g * 8];
    }
    const int sbase = w * 16 + g * 4;
#pragma unroll
    for (int et = 0; et < 4; et++) {
      const int e = et * 16 + m;
      bfrag BW0 = cvt8(outw + (size_t)e * 64 + g * 8);
      bfrag BW1 = cvt8(outw + (size_t)e * 64 + 32 + g * 8);
      const float ob = outb[e];
      float4 pv = *(const float4*)(posg + (size_t)e * 64 + sbase);
#pragma unroll
      for (int it = 0; it < 2; it++) {
        const size_t xoff = (size_t)(b0 + it) * 4096;
        f32x4 c = {0.f, 0.f, 0.f, 0.f};
        c = MFMA16(A0[it], BW0, c);           // col=e, rows=s (4 consec/lane)
        c = MFMA16(A1[it], BW1, c);
        float4 xv = *(const float4*)(xg + xoff + (size_t)e * 64 + sbase);
        float4 o;
        o.x = c[0] + ob + xv.x + pv.x;
        o.y = c[1] + ob + xv.y + pv.y;
        o.z = c[2] + ob + xv.z + pv.z;
        o.w = c[3] + ob + xv.w + pv.w;
        *(float4*)(outg + xoff + (size_t)e * 64 + sbase) = o;
      }
    }
  }
}

extern "C" void kernel_launch(void* const* d_in, const int* in_sizes, int n_in,
                              void* d_out, int out_size, void* d_ws, size_t ws_size,
                              hipStream_t stream) {
  const float* xg   = (const float*)d_in[0];
  const float* pos  = (const float*)d_in[1];
  const float* gam  = (const float*)d_in[2];
  const float* bet  = (const float*)d_in[3];
  const float* qkvw = (const float*)d_in[4];
  const float* qkvb = (const float*)d_in[5];
  const float* outw = (const float*)d_in[6];
  const float* outb = (const float*)d_in[7];
  const float* cb   = (const float*)d_in[8];
  float* out = (float*)d_out;
  const int B = in_sizes[0] / (64 * 64);   // 4096
  hipLaunchKernelGGL(chess_attn_kernel, dim3(B / 2), dim3(256), 0, stream,
                     xg, pos, gam, bet, qkvw, qkvb, outw, outb, cb, out);
}